// Round 3
// baseline (2069.400 us; speedup 1.0000x reference)
//
#include <hip/hip_runtime.h>
#include <cstdint>

typedef unsigned short u16;
typedef __bf16 bf16x8 __attribute__((ext_vector_type(8)));
typedef float f32x4 __attribute__((ext_vector_type(4)));

#define BM 128
#define BN 128
#define BK 32
#define CL 256   // scan chunk length
#define NC 16    // chunks per channel (CL*NC = 4096 = L)
#define DI 2048  // d_inner
#define DM 1024  // d_model
#define LSEQ 4096

__device__ __forceinline__ float bf2f(u16 u) {
    union { uint32_t i; float f; } v; v.i = ((uint32_t)u) << 16; return v.f;
}
__device__ __forceinline__ u16 f2bf(float f) {
    union { float f; uint32_t i; } v; v.f = f;
    uint32_t r = v.i + 0x7fffu + ((v.i >> 16) & 1u);
    return (u16)(r >> 16);
}

// ---------------------------------------------------------------------------
// f32 -> bf16 cast (vectorized x4)
// ---------------------------------------------------------------------------
__global__ __launch_bounds__(256)
void cast_f2b(const float* __restrict__ src, u16* __restrict__ dst, long n)
{
    long i = ((long)blockIdx.x * 256 + threadIdx.x) * 4;
    if (i >= n) return;
    float4 v = *(const float4*)(src + i);
    ushort4 o;
    o.x = f2bf(v.x); o.y = f2bf(v.y); o.z = f2bf(v.z); o.w = f2bf(v.w);
    *(ushort4*)(dst + i) = o;
}

// ---------------------------------------------------------------------------
// GEMM: C[M,N] = A[M,K] * W[N,K]^T  (both K-contiguous, bf16 in, fp32 acc)
// EPI: 0 = in_proj split->(x1,z) bf16 | 1 = +bias,softplus->dt bf16
//      2 = sigmoid*xc->u bf16        | 3 = tanh->Ct bf16 | 4 = f32 store
// ---------------------------------------------------------------------------
template<int EPI>
__global__ __launch_bounds__(256)
void gemm_bt(const u16* __restrict__ A, const u16* __restrict__ W,
             int M, int N, int K,
             const float* __restrict__ auxf,    // bias (EPI1)
             const u16* __restrict__ auxb,      // xc (EPI2)
             u16* __restrict__ outb0, u16* __restrict__ outb1,
             float* __restrict__ outf)
{
    __shared__ __align__(16) u16 As[BM][BK + 8];
    __shared__ __align__(16) u16 Bs[BN][BK + 8];

    const int t    = threadIdx.x;
    const int lane = t & 63;
    const int wave = t >> 6;
    const int quad = lane >> 4;
    const int l16  = lane & 15;
    const int wm   = wave >> 1, wn = wave & 1;
    const long m0  = (long)blockIdx.y * BM;
    const long n0  = (long)blockIdx.x * BN;

    const int r   = t >> 1;          // 0..127 tile row
    const int c16 = (t & 1) * 16;    // 0 or 16 within BK

    const u16* gA = A + (size_t)(m0 + r) * K + c16;
    const u16* gW = W + (size_t)(n0 + r) * K + c16;

    f32x4 acc[4][4];
#pragma unroll
    for (int i = 0; i < 4; ++i)
#pragma unroll
        for (int j = 0; j < 4; ++j)
            acc[i][j] = (f32x4){0.f, 0.f, 0.f, 0.f};

    for (int k0 = 0; k0 < K; k0 += BK) {
        uint4 a0 = *(const uint4*)(gA + k0);
        uint4 a1 = *(const uint4*)(gA + k0 + 8);
        uint4 b0 = *(const uint4*)(gW + k0);
        uint4 b1 = *(const uint4*)(gW + k0 + 8);
        __syncthreads();
        *(uint4*)&As[r][c16]     = a0;
        *(uint4*)&As[r][c16 + 8] = a1;
        *(uint4*)&Bs[r][c16]     = b0;
        *(uint4*)&Bs[r][c16 + 8] = b1;
        __syncthreads();

        bf16x8 af[4], bfr[4];
#pragma unroll
        for (int i = 0; i < 4; ++i)
            af[i] = *(const bf16x8*)&As[wm * 64 + i * 16 + l16][quad * 8];
#pragma unroll
        for (int j = 0; j < 4; ++j)
            bfr[j] = *(const bf16x8*)&Bs[wn * 64 + j * 16 + l16][quad * 8];
#pragma unroll
        for (int i = 0; i < 4; ++i)
#pragma unroll
            for (int j = 0; j < 4; ++j)
                acc[i][j] = __builtin_amdgcn_mfma_f32_16x16x32_bf16(af[i], bfr[j], acc[i][j], 0, 0, 0);
    }

    // epilogue: C/D layout col=lane&15, row=quad*4+reg  [m89/m91-verified]
#pragma unroll
    for (int i = 0; i < 4; ++i) {
#pragma unroll
        for (int j = 0; j < 4; ++j) {
            const long nc = n0 + wn * 64 + j * 16 + l16;
#pragma unroll
            for (int rg = 0; rg < 4; ++rg) {
                const long mr = m0 + wm * 64 + i * 16 + quad * 4 + rg;
                float v = acc[i][j][rg];
                if (EPI == 0) {
                    if (nc < DI) outb0[mr * DI + nc] = f2bf(v);
                    else         outb1[mr * DI + (nc - DI)] = f2bf(v);
                } else if (EPI == 1) {
                    v += auxf[nc];
                    float sp = (v > 20.f) ? v : log1pf(expf(v));
                    outb0[mr * DI + nc] = f2bf(sp);
                } else if (EPI == 2) {
                    float bt  = 1.f / (1.f + expf(-v));
                    float xcv = bf2f(auxb[mr * DI + nc]);
                    outb0[mr * DI + nc] = f2bf(xcv * bt);
                } else if (EPI == 3) {
                    outb0[mr * DI + nc] = f2bf(tanhf(v));
                } else {
                    outf[mr * DM + nc] = v;
                }
            }
        }
    }
}

// ---------------------------------------------------------------------------
// depthwise causal conv1d (k=4) + bias + silu : x1[nb,L,D](bf16) -> xc (bf16)
// ---------------------------------------------------------------------------
__global__ __launch_bounds__(256)
void conv_silu(const u16* __restrict__ x1, const float* __restrict__ Wc,
               const float* __restrict__ bc, u16* __restrict__ xc)
{
    const long idx = (long)blockIdx.x * 256 + threadIdx.x;   // b*L*D + l*D + d
    const int d  = (int)(idx & (DI - 1));
    const long bl = idx >> 11;            // b*L + l
    const int l  = (int)(bl & (LSEQ - 1));
    float acc = bc[d];
#pragma unroll
    for (int tp = 0; tp < 4; ++tp) {
        int ls = l - 3 + tp;
        if (ls >= 0)
            acc += bf2f(x1[(bl - 3 + tp) * DI + d]) * Wc[d * 4 + tp];
    }
    float s = acc / (1.f + expf(-acc));   // silu
    xc[idx] = f2bf(s);
}

// ---------------------------------------------------------------------------
// scan (h_l = exp(la_l)*h_{l-1} + beta_l), chunked 3-pass
// ---------------------------------------------------------------------------
__global__ __launch_bounds__(256)
void scan_a(const u16* __restrict__ dt, const u16* __restrict__ u,
            const float* __restrict__ A_log,
            float* __restrict__ sumlog, float* __restrict__ hend, int nbD)
{
    const int d = blockIdx.x * 256 + threadIdx.x;   // 0..2047
    const int b = blockIdx.y;
    const int c = blockIdx.z;
    const float Ad = -expf(A_log[d]);
    size_t base = ((size_t)b * LSEQ + (size_t)c * CL) * DI + d;
    float pu = (c == 0) ? 0.f : bf2f(u[base - DI]);
    float sl = 0.f, h = 0.f;
    for (int s = 0; s < CL; ++s) {
        float dtv = bf2f(dt[base]);
        float uv  = bf2f(u[base]);
        float la  = fminf(fmaxf(Ad * dtv, -10.f), -1e-4f);
        sl += la;
        h = expf(la) * h + dtv * 0.5f * (pu + uv);
        pu = uv;
        base += DI;
    }
    const int chn = b * DI + d;
    sumlog[c * nbD + chn] = sl;
    hend[c * nbD + chn]   = h;
}

__global__ __launch_bounds__(256)
void scan_b(const float* __restrict__ sumlog, const float* __restrict__ hend,
            float* __restrict__ hin, int nbD)
{
    const int chn = blockIdx.x * 256 + threadIdx.x;   // 0..nbD-1
    float carry = 0.f;
#pragma unroll
    for (int c = 0; c < NC; ++c) {
        hin[c * nbD + chn] = carry;
        carry = expf(sumlog[c * nbD + chn]) * carry + hend[c * nbD + chn];
    }
}

__global__ __launch_bounds__(256)
void scan_c(const u16* __restrict__ dt, const u16* __restrict__ u,
            const float* __restrict__ A_log, const float* __restrict__ hin,
            const u16* __restrict__ Ct, const u16* __restrict__ z,
            u16* __restrict__ y, int nbD)
{
    const int d = blockIdx.x * 256 + threadIdx.x;
    const int b = blockIdx.y;
    const int c = blockIdx.z;
    const float Ad = -expf(A_log[d]);
    size_t base = ((size_t)b * LSEQ + (size_t)c * CL) * DI + d;
    float pu = (c == 0) ? 0.f : bf2f(u[base - DI]);
    const int chn = b * DI + d;
    float h = hin[c * nbD + chn];
    for (int s = 0; s < CL; ++s) {
        float dtv = bf2f(dt[base]);
        float uv  = bf2f(u[base]);
        float la  = fminf(fmaxf(Ad * dtv, -10.f), -1e-4f);
        h = expf(la) * h + dtv * 0.5f * (pu + uv);
        pu = uv;
        float ct = bf2f(Ct[base]);
        float zv = bf2f(z[base]);
        float sz = zv / (1.f + expf(-zv));   // silu(z)
        y[base] = f2bf(h * ct * sz);
        base += DI;
    }
}

// ---------------------------------------------------------------------------
struct WeightsB {   // bf16 casts of the big weights (in ws)
    const u16 *Wi, *Wdt, *WB, *WC, *Wo;
};
struct SmallF {     // small f32 inputs consumed directly
    const float *Wconv, *bconv, *bdt, *A_log;
};

static void run_pipeline(int nb, const float* x, float* out, char* ws,
                         const WeightsB& wb, const SmallF& sf, hipStream_t stream)
{
    const int Mrows = nb * LSEQ;
    const size_t nE = (size_t)Mrows * DI;    // elements per big buffer
    const size_t nX = (size_t)Mrows * DM;
    const int nbD = nb * DI;

    char* p = ws;
    u16* xb = (u16*)p; p += nX * 2;   // x cast to bf16
    u16* b0 = (u16*)p; p += nE * 2;   // x1, then dt
    u16* b1 = (u16*)p; p += nE * 2;   // z
    u16* b2 = (u16*)p; p += nE * 2;   // xc
    u16* b3 = (u16*)p; p += nE * 2;   // u
    u16* b4 = (u16*)p; p += nE * 2;   // Ct, then y (in-place in scan_c)
    float* sumlog = (float*)p; p += (size_t)nbD * NC * 4;
    float* hend   = (float*)p; p += (size_t)nbD * NC * 4;
    float* hin    = (float*)p; p += (size_t)nbD * NC * 4;

    u16* x1 = b0; u16* z = b1; u16* xc = b2;
    u16* dt = b0; u16* u  = b3; u16* Ct = b4; u16* y = b4;

    dim3 blk(256);

    // 0) cast activations input
    cast_f2b<<<dim3((unsigned)(nX / 1024)), blk, 0, stream>>>(x, xb, (long)nX);

    // 1) in_proj: xz = x @ Wi^T -> (x1, z)
    gemm_bt<0><<<dim3(2 * DI / BN, Mrows / BM), blk, 0, stream>>>(
        xb, wb.Wi, Mrows, 2 * DI, DM, nullptr, nullptr, x1, z, nullptr);

    // 2) causal depthwise conv + silu
    conv_silu<<<dim3((unsigned)(nE / 256)), blk, 0, stream>>>(x1, sf.Wconv, sf.bconv, xc);

    // 3) projections (fused activations); dt overwrites x1 (dead after conv)
    gemm_bt<1><<<dim3(DI / BN, Mrows / BM), blk, 0, stream>>>(
        xc, wb.Wdt, Mrows, DI, DI, sf.bdt, nullptr, dt, nullptr, nullptr);
    gemm_bt<2><<<dim3(DI / BN, Mrows / BM), blk, 0, stream>>>(
        xc, wb.WB, Mrows, DI, DI, nullptr, xc, u, nullptr, nullptr);
    gemm_bt<3><<<dim3(DI / BN, Mrows / BM), blk, 0, stream>>>(
        xc, wb.WC, Mrows, DI, DI, nullptr, nullptr, Ct, nullptr, nullptr);

    // 4) chunked scan + fuse y = h * Ct * silu(z); y overwrites Ct in-place
    scan_a<<<dim3(DI / 256, nb, NC), blk, 0, stream>>>(dt, u, sf.A_log, sumlog, hend, nbD);
    scan_b<<<dim3(nbD / 256), blk, 0, stream>>>(sumlog, hend, hin, nbD);
    scan_c<<<dim3(DI / 256, nb, NC), blk, 0, stream>>>(dt, u, sf.A_log, hin, Ct, z, y, nbD);

    // 5) out_proj -> out (f32)
    gemm_bt<4><<<dim3(DM / BN, Mrows / BM), blk, 0, stream>>>(
        y, wb.Wo, Mrows, DM, DI, nullptr, nullptr, nullptr, nullptr, out);
}

extern "C" void kernel_launch(void* const* d_in, const int* in_sizes, int n_in,
                              void* d_out, int out_size, void* d_ws, size_t ws_size,
                              hipStream_t stream)
{
    const float* x     = (const float*)d_in[0];
    const float* Wi    = (const float*)d_in[1];
    const float* Wconv = (const float*)d_in[2];
    const float* bconv = (const float*)d_in[3];
    const float* Wdt   = (const float*)d_in[4];
    const float* bdt   = (const float*)d_in[5];
    const float* WB    = (const float*)d_in[6];
    const float* WC    = (const float*)d_in[7];
    const float* Wo    = (const float*)d_in[8];
    const float* A_log = (const float*)d_in[9];

    const size_t nWi = (size_t)2 * DI * DM;   // 4.19M
    const size_t nWp = (size_t)DI * DI;       // 4.19M
    const size_t nWo = (size_t)DM * DI;       // 2.10M

    // weight casts live at the END of ws (shared by both paths)
    const size_t wbytes = (nWi + 3 * nWp + nWo) * 2;
    char* wtop = (char*)d_ws + ws_size - wbytes;
    char* q = wtop;
    u16* Wi_b  = (u16*)q; q += nWi * 2;
    u16* Wdt_b = (u16*)q; q += nWp * 2;
    u16* WB_b  = (u16*)q; q += nWp * 2;
    u16* WC_b  = (u16*)q; q += nWp * 2;
    u16* Wo_b  = (u16*)q; q += nWo * 2;

    dim3 blk(256);
    cast_f2b<<<dim3((unsigned)(nWi / 1024)), blk, 0, stream>>>(Wi,  Wi_b,  (long)nWi);
    cast_f2b<<<dim3((unsigned)(nWp / 1024)), blk, 0, stream>>>(Wdt, Wdt_b, (long)nWp);
    cast_f2b<<<dim3((unsigned)(nWp / 1024)), blk, 0, stream>>>(WB,  WB_b,  (long)nWp);
    cast_f2b<<<dim3((unsigned)(nWp / 1024)), blk, 0, stream>>>(WC,  WC_b,  (long)nWp);
    cast_f2b<<<dim3((unsigned)(nWo / 1024)), blk, 0, stream>>>(Wo,  Wo_b,  (long)nWo);

    WeightsB wb{Wi_b, Wdt_b, WB_b, WC_b, Wo_b};
    SmallF   sf{Wconv, bconv, bdt, A_log};

    // big-buffer need for nb batches:
    auto need = [&](int nb) -> size_t {
        size_t nE = (size_t)nb * LSEQ * DI;
        size_t nX = (size_t)nb * LSEQ * DM;
        return nX * 2 + 5 * nE * 2 + 3 * (size_t)nb * DI * NC * 4;
    };

    if (ws_size >= need(4) + wbytes) {
        run_pipeline(4, x, (float*)d_out, (char*)d_ws, wb, sf, stream);
    } else {
        for (int b = 0; b < 4; ++b)
            run_pipeline(1, x + (size_t)b * LSEQ * DM,
                         (float*)d_out + (size_t)b * LSEQ * DM,
                         (char*)d_ws, wb, sf, stream);
    }
}

// Round 4
// 1618.953 us; speedup vs baseline: 1.2782x; 1.2782x over previous
//
#include <hip/hip_runtime.h>
#include <cstdint>

typedef unsigned short u16;
typedef unsigned int u32;
typedef __bf16 bf16x8 __attribute__((ext_vector_type(8)));
typedef float f32x4 __attribute__((ext_vector_type(4)));

#define BM 128
#define BN 128
#define BK 32
#define CL 256   // scan chunk length
#define NC 16    // chunks per channel (CL*NC = 4096 = L)
#define DI 2048  // d_inner
#define DM 1024  // d_model
#define LSEQ 4096

__device__ __forceinline__ float bf2f(u16 u) {
    union { uint32_t i; float f; } v; v.i = ((uint32_t)u) << 16; return v.f;
}
__device__ __forceinline__ u16 f2bf(float f) {
    union { float f; uint32_t i; } v; v.f = f;
    uint32_t r = v.i + 0x7fffu + ((v.i >> 16) & 1u);
    return (u16)(r >> 16);
}

// async global->LDS, 16B per lane; LDS dst = base + lane*16 (wave-uniform base)
__device__ __forceinline__ void gl_lds16(const u16* g, u16* l) {
    __builtin_amdgcn_global_load_lds(
        (const __attribute__((address_space(1))) u32*)g,
        (__attribute__((address_space(3))) u32*)l, 16, 0, 0);
}

// ---------------------------------------------------------------------------
// f32 -> bf16 cast (vectorized x4)
// ---------------------------------------------------------------------------
__global__ __launch_bounds__(256)
void cast_f2b(const float* __restrict__ src, u16* __restrict__ dst, long n)
{
    long i = ((long)blockIdx.x * 256 + threadIdx.x) * 4;
    if (i >= n) return;
    float4 v = *(const float4*)(src + i);
    ushort4 o;
    o.x = f2bf(v.x); o.y = f2bf(v.y); o.z = f2bf(v.z); o.w = f2bf(v.w);
    *(ushort4*)(dst + i) = o;
}

// ---------------------------------------------------------------------------
// GEMM (m97-style): C[M,N] = A[M,K] * W[N,K]^T, bf16 in, fp32 acc.
// Staging via global_load_lds width-16 into unpadded 128x32 LDS tiles with a
// chunk swizzle: row r holds global 16B-chunk c at slot (c + (r>>1)) & 3.
// EPI: 0 = in_proj split->(x1,z) bf16 | 1 = +bias,softplus->dt bf16
//      2 = sigmoid*xc->u bf16        | 3 = tanh->Ct bf16 | 4 = f32 store
// ---------------------------------------------------------------------------
template<int EPI>
__global__ __launch_bounds__(256)
void gemm_bt(const u16* __restrict__ A, const u16* __restrict__ W,
             int M, int N, int K,
             const float* __restrict__ auxf,    // bias (EPI1)
             const u16* __restrict__ auxb,      // xc (EPI2)
             u16* __restrict__ outb0, u16* __restrict__ outb1,
             float* __restrict__ outf)
{
    __shared__ __align__(16) u16 As[BM * BK];   // 8 KB, row stride 32 elems
    __shared__ __align__(16) u16 Bs[BN * BK];   // 8 KB

    const int t    = threadIdx.x;
    const int lane = t & 63;
    const int w    = t >> 6;
    const int quad = lane >> 4;
    const int l16  = lane & 15;
    const int wm   = w >> 1, wn = w & 1;
    const long m0  = (long)blockIdx.y * BM;
    const long n0  = (long)blockIdx.x * BN;

    // ---- staging lane constants ----
    // inst q covers rows q*16..q*16+15; lane i -> row q*16 + (i>>2), slot i&3
    // global chunk for this slot: cg = ((i&3) - ((i>>3)&3)) & 3   (q-independent)
    const int rr = lane >> 2;
    const int cg = ((lane & 3) - ((lane >> 3) & 3)) & 3;

    const u16* gA0 = A + (size_t)(m0 + (2 * w)     * 16 + rr) * K + cg * 8;
    const u16* gA1 = A + (size_t)(m0 + (2 * w + 1) * 16 + rr) * K + cg * 8;
    const u16* gB0 = W + (size_t)(n0 + (2 * w)     * 16 + rr) * K + cg * 8;
    const u16* gB1 = W + (size_t)(n0 + (2 * w + 1) * 16 + rr) * K + cg * 8;

    u16* lA0 = As + (2 * w)     * 512;   // 512 elems = 1024 B per inst
    u16* lA1 = As + (2 * w + 1) * 512;
    u16* lB0 = Bs + (2 * w)     * 512;
    u16* lB1 = Bs + (2 * w + 1) * 512;

    // ---- fragment read constants ----
    // row r = wm*64 + fi*16 + l16 ; slot = (quad + (l16>>1)) & 3
    const int slotr = (quad + (l16 >> 1)) & 3;
    const u16* rdA = As + (wm * 64 + l16) * 32 + slotr * 8;
    const u16* rdB = Bs + (wn * 64 + l16) * 32 + slotr * 8;

    f32x4 acc[4][4];
#pragma unroll
    for (int i = 0; i < 4; ++i)
#pragma unroll
        for (int j = 0; j < 4; ++j)
            acc[i][j] = (f32x4){0.f, 0.f, 0.f, 0.f};

    for (int k0 = 0; k0 < K; k0 += BK) {
        __syncthreads();                    // prev-iter LDS reads done
        gl_lds16(gA0 + k0, lA0);
        gl_lds16(gA1 + k0, lA1);
        gl_lds16(gB0 + k0, lB0);
        gl_lds16(gB1 + k0, lB1);
        __syncthreads();                    // DMA drained (vmcnt before barrier)

        bf16x8 af[4], bfr[4];
#pragma unroll
        for (int fi = 0; fi < 4; ++fi)
            af[fi] = *(const bf16x8*)(rdA + fi * 512);
#pragma unroll
        for (int fj = 0; fj < 4; ++fj)
            bfr[fj] = *(const bf16x8*)(rdB + fj * 512);
#pragma unroll
        for (int i = 0; i < 4; ++i)
#pragma unroll
            for (int j = 0; j < 4; ++j)
                acc[i][j] = __builtin_amdgcn_mfma_f32_16x16x32_bf16(af[i], bfr[j], acc[i][j], 0, 0, 0);
    }

    // epilogue: C/D layout col=lane&15, row=quad*4+reg  [m89/m91-verified]
#pragma unroll
    for (int i = 0; i < 4; ++i) {
#pragma unroll
        for (int j = 0; j < 4; ++j) {
            const long nc = n0 + wn * 64 + j * 16 + l16;
#pragma unroll
            for (int rg = 0; rg < 4; ++rg) {
                const long mr = m0 + wm * 64 + i * 16 + quad * 4 + rg;
                float v = acc[i][j][rg];
                if (EPI == 0) {
                    if (nc < DI) outb0[mr * DI + nc] = f2bf(v);
                    else         outb1[mr * DI + (nc - DI)] = f2bf(v);
                } else if (EPI == 1) {
                    v += auxf[nc];
                    float sp = (v > 20.f) ? v : log1pf(expf(v));
                    outb0[mr * DI + nc] = f2bf(sp);
                } else if (EPI == 2) {
                    float bt  = 1.f / (1.f + expf(-v));
                    float xcv = bf2f(auxb[mr * DI + nc]);
                    outb0[mr * DI + nc] = f2bf(xcv * bt);
                } else if (EPI == 3) {
                    outb0[mr * DI + nc] = f2bf(tanhf(v));
                } else {
                    outf[mr * DM + nc] = v;
                }
            }
        }
    }
}

// ---------------------------------------------------------------------------
// depthwise causal conv1d (k=4) + bias + silu : x1[nb,L,D](bf16) -> xc (bf16)
// ---------------------------------------------------------------------------
__global__ __launch_bounds__(256)
void conv_silu(const u16* __restrict__ x1, const float* __restrict__ Wc,
               const float* __restrict__ bc, u16* __restrict__ xc)
{
    const long idx = (long)blockIdx.x * 256 + threadIdx.x;   // b*L*D + l*D + d
    const int d  = (int)(idx & (DI - 1));
    const long bl = idx >> 11;            // b*L + l
    const int l  = (int)(bl & (LSEQ - 1));
    float acc = bc[d];
#pragma unroll
    for (int tp = 0; tp < 4; ++tp) {
        int ls = l - 3 + tp;
        if (ls >= 0)
            acc += bf2f(x1[(bl - 3 + tp) * DI + d]) * Wc[d * 4 + tp];
    }
    float s = acc / (1.f + expf(-acc));   // silu
    xc[idx] = f2bf(s);
}

// ---------------------------------------------------------------------------
// scan (h_l = exp(la_l)*h_{l-1} + beta_l), chunked 3-pass
// ---------------------------------------------------------------------------
__global__ __launch_bounds__(256)
void scan_a(const u16* __restrict__ dt, const u16* __restrict__ u,
            const float* __restrict__ A_log,
            float* __restrict__ sumlog, float* __restrict__ hend, int nbD)
{
    const int d = blockIdx.x * 256 + threadIdx.x;   // 0..2047
    const int b = blockIdx.y;
    const int c = blockIdx.z;
    const float Ad = -expf(A_log[d]);
    size_t base = ((size_t)b * LSEQ + (size_t)c * CL) * DI + d;
    float pu = (c == 0) ? 0.f : bf2f(u[base - DI]);
    float sl = 0.f, h = 0.f;
    for (int s = 0; s < CL; ++s) {
        float dtv = bf2f(dt[base]);
        float uv  = bf2f(u[base]);
        float la  = fminf(fmaxf(Ad * dtv, -10.f), -1e-4f);
        sl += la;
        h = expf(la) * h + dtv * 0.5f * (pu + uv);
        pu = uv;
        base += DI;
    }
    const int chn = b * DI + d;
    sumlog[c * nbD + chn] = sl;
    hend[c * nbD + chn]   = h;
}

__global__ __launch_bounds__(256)
void scan_b(const float* __restrict__ sumlog, const float* __restrict__ hend,
            float* __restrict__ hin, int nbD)
{
    const int chn = blockIdx.x * 256 + threadIdx.x;   // 0..nbD-1
    float carry = 0.f;
#pragma unroll
    for (int c = 0; c < NC; ++c) {
        hin[c * nbD + chn] = carry;
        carry = expf(sumlog[c * nbD + chn]) * carry + hend[c * nbD + chn];
    }
}

__global__ __launch_bounds__(256)
void scan_c(const u16* __restrict__ dt, const u16* __restrict__ u,
            const float* __restrict__ A_log, const float* __restrict__ hin,
            const u16* __restrict__ Ct, const u16* __restrict__ z,
            u16* __restrict__ y, int nbD)
{
    const int d = blockIdx.x * 256 + threadIdx.x;
    const int b = blockIdx.y;
    const int c = blockIdx.z;
    const float Ad = -expf(A_log[d]);
    size_t base = ((size_t)b * LSEQ + (size_t)c * CL) * DI + d;
    float pu = (c == 0) ? 0.f : bf2f(u[base - DI]);
    const int chn = b * DI + d;
    float h = hin[c * nbD + chn];
    for (int s = 0; s < CL; ++s) {
        float dtv = bf2f(dt[base]);
        float uv  = bf2f(u[base]);
        float la  = fminf(fmaxf(Ad * dtv, -10.f), -1e-4f);
        h = expf(la) * h + dtv * 0.5f * (pu + uv);
        pu = uv;
        float ct = bf2f(Ct[base]);
        float zv = bf2f(z[base]);
        float sz = zv / (1.f + expf(-zv));   // silu(z)
        y[base] = f2bf(h * ct * sz);
        base += DI;
    }
}

// ---------------------------------------------------------------------------
struct WeightsB {   // bf16 casts of the big weights (in ws)
    const u16 *Wi, *Wdt, *WB, *WC, *Wo;
};
struct SmallF {     // small f32 inputs consumed directly
    const float *Wconv, *bconv, *bdt, *A_log;
};

static void run_pipeline(int nb, const float* x, float* out, char* ws,
                         const WeightsB& wb, const SmallF& sf, hipStream_t stream)
{
    const int Mrows = nb * LSEQ;
    const size_t nE = (size_t)Mrows * DI;    // elements per big buffer
    const size_t nX = (size_t)Mrows * DM;
    const int nbD = nb * DI;

    char* p = ws;
    u16* xb = (u16*)p; p += nX * 2;   // x cast to bf16
    u16* b0 = (u16*)p; p += nE * 2;   // x1, then dt
    u16* b1 = (u16*)p; p += nE * 2;   // z
    u16* b2 = (u16*)p; p += nE * 2;   // xc
    u16* b3 = (u16*)p; p += nE * 2;   // u
    u16* b4 = (u16*)p; p += nE * 2;   // Ct, then y (in-place in scan_c)
    float* sumlog = (float*)p; p += (size_t)nbD * NC * 4;
    float* hend   = (float*)p; p += (size_t)nbD * NC * 4;
    float* hin    = (float*)p; p += (size_t)nbD * NC * 4;

    u16* x1 = b0; u16* z = b1; u16* xc = b2;
    u16* dt = b0; u16* u  = b3; u16* Ct = b4; u16* y = b4;

    dim3 blk(256);

    // 0) cast activations input
    cast_f2b<<<dim3((unsigned)(nX / 1024)), blk, 0, stream>>>(x, xb, (long)nX);

    // 1) in_proj: xz = x @ Wi^T -> (x1, z)
    gemm_bt<0><<<dim3(2 * DI / BN, Mrows / BM), blk, 0, stream>>>(
        xb, wb.Wi, Mrows, 2 * DI, DM, nullptr, nullptr, x1, z, nullptr);

    // 2) causal depthwise conv + silu
    conv_silu<<<dim3((unsigned)(nE / 256)), blk, 0, stream>>>(x1, sf.Wconv, sf.bconv, xc);

    // 3) projections (fused activations); dt overwrites x1 (dead after conv)
    gemm_bt<1><<<dim3(DI / BN, Mrows / BM), blk, 0, stream>>>(
        xc, wb.Wdt, Mrows, DI, DI, sf.bdt, nullptr, dt, nullptr, nullptr);
    gemm_bt<2><<<dim3(DI / BN, Mrows / BM), blk, 0, stream>>>(
        xc, wb.WB, Mrows, DI, DI, nullptr, xc, u, nullptr, nullptr);
    gemm_bt<3><<<dim3(DI / BN, Mrows / BM), blk, 0, stream>>>(
        xc, wb.WC, Mrows, DI, DI, nullptr, nullptr, Ct, nullptr, nullptr);

    // 4) chunked scan + fuse y = h * Ct * silu(z); y overwrites Ct in-place
    scan_a<<<dim3(DI / 256, nb, NC), blk, 0, stream>>>(dt, u, sf.A_log, sumlog, hend, nbD);
    scan_b<<<dim3(nbD / 256), blk, 0, stream>>>(sumlog, hend, hin, nbD);
    scan_c<<<dim3(DI / 256, nb, NC), blk, 0, stream>>>(dt, u, sf.A_log, hin, Ct, z, y, nbD);

    // 5) out_proj -> out (f32)
    gemm_bt<4><<<dim3(DM / BN, Mrows / BM), blk, 0, stream>>>(
        y, wb.Wo, Mrows, DM, DI, nullptr, nullptr, nullptr, nullptr, out);
}

extern "C" void kernel_launch(void* const* d_in, const int* in_sizes, int n_in,
                              void* d_out, int out_size, void* d_ws, size_t ws_size,
                              hipStream_t stream)
{
    const float* x     = (const float*)d_in[0];
    const float* Wi    = (const float*)d_in[1];
    const float* Wconv = (const float*)d_in[2];
    const float* bconv = (const float*)d_in[3];
    const float* Wdt   = (const float*)d_in[4];
    const float* bdt   = (const float*)d_in[5];
    const float* WB    = (const float*)d_in[6];
    const float* WC    = (const float*)d_in[7];
    const float* Wo    = (const float*)d_in[8];
    const float* A_log = (const float*)d_in[9];

    const size_t nWi = (size_t)2 * DI * DM;   // 4.19M
    const size_t nWp = (size_t)DI * DI;       // 4.19M
    const size_t nWo = (size_t)DM * DI;       // 2.10M

    // weight casts live at the END of ws (shared by both paths)
    const size_t wbytes = (nWi + 3 * nWp + nWo) * 2;
    char* wtop = (char*)d_ws + ws_size - wbytes;
    char* q = wtop;
    u16* Wi_b  = (u16*)q; q += nWi * 2;
    u16* Wdt_b = (u16*)q; q += nWp * 2;
    u16* WB_b  = (u16*)q; q += nWp * 2;
    u16* WC_b  = (u16*)q; q += nWp * 2;
    u16* Wo_b  = (u16*)q; q += nWo * 2;

    dim3 blk(256);
    cast_f2b<<<dim3((unsigned)(nWi / 1024)), blk, 0, stream>>>(Wi,  Wi_b,  (long)nWi);
    cast_f2b<<<dim3((unsigned)(nWp / 1024)), blk, 0, stream>>>(Wdt, Wdt_b, (long)nWp);
    cast_f2b<<<dim3((unsigned)(nWp / 1024)), blk, 0, stream>>>(WB,  WB_b,  (long)nWp);
    cast_f2b<<<dim3((unsigned)(nWp / 1024)), blk, 0, stream>>>(WC,  WC_b,  (long)nWp);
    cast_f2b<<<dim3((unsigned)(nWo / 1024)), blk, 0, stream>>>(Wo,  Wo_b,  (long)nWo);

    WeightsB wb{Wi_b, Wdt_b, WB_b, WC_b, Wo_b};
    SmallF   sf{Wconv, bconv, bdt, A_log};

    // big-buffer need for nb batches:
    auto need = [&](int nb) -> size_t {
        size_t nE = (size_t)nb * LSEQ * DI;
        size_t nX = (size_t)nb * LSEQ * DM;
        return nX * 2 + 5 * nE * 2 + 3 * (size_t)nb * DI * NC * 4;
    };

    if (ws_size >= need(4) + wbytes) {
        run_pipeline(4, x, (float*)d_out, (char*)d_ws, wb, sf, stream);
    } else if (ws_size >= need(2) + wbytes) {
        for (int b = 0; b < 4; b += 2)
            run_pipeline(2, x + (size_t)b * LSEQ * DM,
                         (float*)d_out + (size_t)b * LSEQ * DM,
                         (char*)d_ws, wb, sf, stream);
    } else {
        for (int b = 0; b < 4; ++b)
            run_pipeline(1, x + (size_t)b * LSEQ * DM,
                         (float*)d_out + (size_t)b * LSEQ * DM,
                         (char*)d_ws, wb, sf, stream);
    }
}

// Round 5
// 1433.035 us; speedup vs baseline: 1.4441x; 1.1297x over previous
//
#include <hip/hip_runtime.h>
#include <cstdint>

typedef unsigned short u16;
typedef unsigned int u32;
typedef __bf16 bf16x8 __attribute__((ext_vector_type(8)));
typedef float f32x4 __attribute__((ext_vector_type(4)));

#define BM 128
#define BN 128
#define BK 32
#define CL 256   // scan chunk length
#define NC 16    // chunks per channel (CL*NC = 4096 = L)
#define DI 2048  // d_inner
#define DM 1024  // d_model
#define LSEQ 4096

__device__ __forceinline__ float bf2f(u16 u) {
    union { uint32_t i; float f; } v; v.i = ((uint32_t)u) << 16; return v.f;
}
__device__ __forceinline__ u16 f2bf(float f) {
    union { float f; uint32_t i; } v; v.f = f;
    uint32_t r = v.i + 0x7fffu + ((v.i >> 16) & 1u);
    return (u16)(r >> 16);
}

// async global->LDS, 16B per lane; LDS dst = base + lane*16 (wave-uniform base)
__device__ __forceinline__ void gl_lds16(const u16* g, u16* l) {
    __builtin_amdgcn_global_load_lds(
        (const __attribute__((address_space(1))) u32*)g,
        (__attribute__((address_space(3))) u32*)l, 16, 0, 0);
}

// ---------------------------------------------------------------------------
// f32 -> bf16 cast (vectorized x4)
// ---------------------------------------------------------------------------
__global__ __launch_bounds__(256)
void cast_f2b(const float* __restrict__ src, u16* __restrict__ dst, long n)
{
    long i = ((long)blockIdx.x * 256 + threadIdx.x) * 4;
    if (i >= n) return;
    float4 v = *(const float4*)(src + i);
    ushort4 o;
    o.x = f2bf(v.x); o.y = f2bf(v.y); o.z = f2bf(v.z); o.w = f2bf(v.w);
    *(ushort4*)(dst + i) = o;
}

// ---------------------------------------------------------------------------
// GEMM (m97-style): C[M,N] = A[M,K] * W[N,K]^T, bf16 in, fp32 acc.
// Staging via global_load_lds width-16 into unpadded 128x32 LDS tiles with a
// chunk swizzle: row r holds global 16B-chunk c at slot (c + (r>>1)) & 3.
// EPI 0: in_proj  N=4096, split -> x1(ob0), z(ob1)          [bf16]
// EPI 1: fused proj N=6144, group nc>>11: 0 softplus+bias->dt(ob0),
//        1 sigmoid*xc(auxb)->u(ob1), 2 tanh->Ct(ob2)        [bf16]
// EPI 2: out_proj N=1024 -> f32 (outf)
// ---------------------------------------------------------------------------
template<int EPI>
__global__ __launch_bounds__(256, 4)
void gemm_bt(const u16* __restrict__ A, const u16* __restrict__ W,
             int M, int N, int K,
             const float* __restrict__ auxf,    // bias bdt (EPI1)
             const u16* __restrict__ auxb,      // xc (EPI1)
             u16* __restrict__ ob0, u16* __restrict__ ob1,
             u16* __restrict__ ob2, float* __restrict__ outf)
{
    __shared__ __align__(16) u16 As[BM * BK];   // 8 KB, row stride 32 elems
    __shared__ __align__(16) u16 Bs[BN * BK];   // 8 KB

    const int t    = threadIdx.x;
    const int lane = t & 63;
    const int w    = t >> 6;
    const int quad = lane >> 4;
    const int l16  = lane & 15;
    const int wm   = w >> 1, wn = w & 1;
    const long m0  = (long)blockIdx.y * BM;
    const long n0  = (long)blockIdx.x * BN;

    // ---- staging lane constants ----
    // inst q covers rows q*16..q*16+15; lane i -> row q*16 + (i>>2), slot i&3
    // global chunk for this slot: cg = ((i&3) - ((i>>3)&3)) & 3
    const int rr = lane >> 2;
    const int cg = ((lane & 3) - ((lane >> 3) & 3)) & 3;

    const u16* gA0 = A + (size_t)(m0 + (2 * w)     * 16 + rr) * K + cg * 8;
    const u16* gA1 = A + (size_t)(m0 + (2 * w + 1) * 16 + rr) * K + cg * 8;
    const u16* gB0 = W + (size_t)(n0 + (2 * w)     * 16 + rr) * K + cg * 8;
    const u16* gB1 = W + (size_t)(n0 + (2 * w + 1) * 16 + rr) * K + cg * 8;

    u16* lA0 = As + (2 * w)     * 512;
    u16* lA1 = As + (2 * w + 1) * 512;
    u16* lB0 = Bs + (2 * w)     * 512;
    u16* lB1 = Bs + (2 * w + 1) * 512;

    // ---- fragment read constants ----
    const int slotr = (quad + (l16 >> 1)) & 3;
    const u16* rdA = As + (wm * 64 + l16) * 32 + slotr * 8;
    const u16* rdB = Bs + (wn * 64 + l16) * 32 + slotr * 8;

    f32x4 acc[4][4];
#pragma unroll
    for (int i = 0; i < 4; ++i)
#pragma unroll
        for (int j = 0; j < 4; ++j)
            acc[i][j] = (f32x4){0.f, 0.f, 0.f, 0.f};

    for (int k0 = 0; k0 < K; k0 += BK) {
        __syncthreads();                    // prev-iter LDS reads done
        gl_lds16(gA0 + k0, lA0);
        gl_lds16(gA1 + k0, lA1);
        gl_lds16(gB0 + k0, lB0);
        gl_lds16(gB1 + k0, lB1);
        __syncthreads();                    // DMA drained

        bf16x8 af[4], bfr[4];
#pragma unroll
        for (int fi = 0; fi < 4; ++fi)
            af[fi] = *(const bf16x8*)(rdA + fi * 512);
#pragma unroll
        for (int fj = 0; fj < 4; ++fj)
            bfr[fj] = *(const bf16x8*)(rdB + fj * 512);
#pragma unroll
        for (int i = 0; i < 4; ++i)
#pragma unroll
            for (int j = 0; j < 4; ++j)
                acc[i][j] = __builtin_amdgcn_mfma_f32_16x16x32_bf16(af[i], bfr[j], acc[i][j], 0, 0, 0);
    }

    // epilogue: C/D layout col=lane&15, row=quad*4+reg  [m89/m91-verified]
#pragma unroll
    for (int i = 0; i < 4; ++i) {
#pragma unroll
        for (int j = 0; j < 4; ++j) {
            const long nc = n0 + wn * 64 + j * 16 + l16;
#pragma unroll
            for (int rg = 0; rg < 4; ++rg) {
                const long mr = m0 + wm * 64 + i * 16 + quad * 4 + rg;
                float v = acc[i][j][rg];
                if (EPI == 0) {
                    if (nc < DI) ob0[mr * DI + nc] = f2bf(v);
                    else         ob1[mr * DI + (nc - DI)] = f2bf(v);
                } else if (EPI == 1) {
                    const int  g   = (int)(nc >> 11);   // block-uniform
                    const long col = nc & (DI - 1);
                    if (g == 0) {
                        v += auxf[col];
                        float sp = (v > 20.f) ? v : log1pf(expf(v));
                        ob0[mr * DI + col] = f2bf(sp);
                    } else if (g == 1) {
                        float bt  = 1.f / (1.f + expf(-v));
                        float xcv = bf2f(auxb[mr * DI + col]);
                        ob1[mr * DI + col] = f2bf(xcv * bt);
                    } else {
                        ob2[mr * DI + col] = f2bf(tanhf(v));
                    }
                } else {
                    outf[mr * DM + nc] = v;
                }
            }
        }
    }
}

// ---------------------------------------------------------------------------
// depthwise causal conv1d (k=4) + bias + silu : x1[nb,L,D](bf16) -> xc (bf16)
// ---------------------------------------------------------------------------
__global__ __launch_bounds__(256)
void conv_silu(const u16* __restrict__ x1, const float* __restrict__ Wc,
               const float* __restrict__ bc, u16* __restrict__ xc)
{
    const long idx = (long)blockIdx.x * 256 + threadIdx.x;   // b*L*D + l*D + d
    const int d  = (int)(idx & (DI - 1));
    const long bl = idx >> 11;            // b*L + l
    const int l  = (int)(bl & (LSEQ - 1));
    float acc = bc[d];
#pragma unroll
    for (int tp = 0; tp < 4; ++tp) {
        int ls = l - 3 + tp;
        if (ls >= 0)
            acc += bf2f(x1[(bl - 3 + tp) * DI + d]) * Wc[d * 4 + tp];
    }
    float s = acc / (1.f + expf(-acc));   // silu
    xc[idx] = f2bf(s);
}

// ---------------------------------------------------------------------------
// scan (h_l = exp(la_l)*h_{l-1} + beta_l), chunked 3-pass
// ---------------------------------------------------------------------------
__global__ __launch_bounds__(256)
void scan_a(const u16* __restrict__ dt, const u16* __restrict__ u,
            const float* __restrict__ A_log,
            float* __restrict__ sumlog, float* __restrict__ hend, int nbD)
{
    const int d = blockIdx.x * 256 + threadIdx.x;   // 0..2047
    const int b = blockIdx.y;
    const int c = blockIdx.z;
    const float Ad = -expf(A_log[d]);
    size_t base = ((size_t)b * LSEQ + (size_t)c * CL) * DI + d;
    float pu = (c == 0) ? 0.f : bf2f(u[base - DI]);
    float sl = 0.f, h = 0.f;
    for (int s = 0; s < CL; ++s) {
        float dtv = bf2f(dt[base]);
        float uv  = bf2f(u[base]);
        float la  = fminf(fmaxf(Ad * dtv, -10.f), -1e-4f);
        sl += la;
        h = expf(la) * h + dtv * 0.5f * (pu + uv);
        pu = uv;
        base += DI;
    }
    const int chn = b * DI + d;
    sumlog[c * nbD + chn] = sl;
    hend[c * nbD + chn]   = h;
}

__global__ __launch_bounds__(256)
void scan_b(const float* __restrict__ sumlog, const float* __restrict__ hend,
            float* __restrict__ hin, int nbD)
{
    const int chn = blockIdx.x * 256 + threadIdx.x;   // 0..nbD-1
    float carry = 0.f;
#pragma unroll
    for (int c = 0; c < NC; ++c) {
        hin[c * nbD + chn] = carry;
        carry = expf(sumlog[c * nbD + chn]) * carry + hend[c * nbD + chn];
    }
}

__global__ __launch_bounds__(256)
void scan_c(const u16* __restrict__ dt, const u16* __restrict__ u,
            const float* __restrict__ A_log, const float* __restrict__ hin,
            const u16* __restrict__ Ct, const u16* __restrict__ z,
            u16* __restrict__ y, int nbD)
{
    const int d = blockIdx.x * 256 + threadIdx.x;
    const int b = blockIdx.y;
    const int c = blockIdx.z;
    const float Ad = -expf(A_log[d]);
    size_t base = ((size_t)b * LSEQ + (size_t)c * CL) * DI + d;
    float pu = (c == 0) ? 0.f : bf2f(u[base - DI]);
    const int chn = b * DI + d;
    float h = hin[c * nbD + chn];
    for (int s = 0; s < CL; ++s) {
        float dtv = bf2f(dt[base]);
        float uv  = bf2f(u[base]);
        float la  = fminf(fmaxf(Ad * dtv, -10.f), -1e-4f);
        h = expf(la) * h + dtv * 0.5f * (pu + uv);
        pu = uv;
        float ct = bf2f(Ct[base]);
        float zv = bf2f(z[base]);
        float sz = zv / (1.f + expf(-zv));   // silu(z)
        y[base] = f2bf(h * ct * sz);
        base += DI;
    }
}

// ---------------------------------------------------------------------------
struct WeightsB {   // bf16 casts of the big weights (in ws)
    const u16 *Wi, *Wcat, *Wo;   // Wcat = [Wdt; WB; WC], 6144 x 2048
};
struct SmallF {     // small f32 inputs consumed directly
    const float *Wconv, *bconv, *bdt, *A_log;
};

static void run_pipeline(int nb, const float* x, float* out, char* ws,
                         const WeightsB& wb, const SmallF& sf, hipStream_t stream)
{
    const int Mrows = nb * LSEQ;
    const size_t nE = (size_t)Mrows * DI;    // elements per big buffer
    const size_t nX = (size_t)Mrows * DM;
    const int nbD = nb * DI;

    char* p = ws;
    u16* b0 = (u16*)p; p += nE * 2;   // x1, then dt
    u16* b1 = (u16*)p; p += nE * 2;   // z
    u16* b2 = (u16*)p; p += nE * 2;   // xc  (first half doubles as xb)
    u16* b3 = (u16*)p; p += nE * 2;   // u
    u16* b4 = (u16*)p; p += nE * 2;   // Ct, then y (in-place in scan_c)
    float* sumlog = (float*)p; p += (size_t)nbD * NC * 4;
    float* hend   = (float*)p; p += (size_t)nbD * NC * 4;
    float* hin    = (float*)p; p += (size_t)nbD * NC * 4;

    u16* xb = b2;                       // x cast; dead before conv writes xc
    u16* x1 = b0; u16* z = b1; u16* xc = b2;
    u16* dt = b0; u16* u  = b3; u16* Ct = b4; u16* y = b4;

    dim3 blk(256);

    // 0) cast activations input (into xc's buffer — released before conv)
    cast_f2b<<<dim3((unsigned)(nX / 1024)), blk, 0, stream>>>(x, xb, (long)nX);

    // 1) in_proj: xz = x @ Wi^T -> (x1, z)
    gemm_bt<0><<<dim3(2 * DI / BN, Mrows / BM), blk, 0, stream>>>(
        xb, wb.Wi, Mrows, 2 * DI, DM, nullptr, nullptr, x1, z, nullptr, nullptr);

    // 2) causal depthwise conv + silu (overwrites xb region)
    conv_silu<<<dim3((unsigned)(nE / 256)), blk, 0, stream>>>(x1, sf.Wconv, sf.bconv, xc);

    // 3) fused dt/B/C projection (one N=6144 GEMM); dt overwrites x1
    gemm_bt<1><<<dim3(3 * DI / BN, Mrows / BM), blk, 0, stream>>>(
        xc, wb.Wcat, Mrows, 3 * DI, DI, sf.bdt, xc, dt, u, Ct, nullptr);

    // 4) chunked scan + fuse y = h * Ct * silu(z); y overwrites Ct in-place
    scan_a<<<dim3(DI / 256, nb, NC), blk, 0, stream>>>(dt, u, sf.A_log, sumlog, hend, nbD);
    scan_b<<<dim3(nbD / 256), blk, 0, stream>>>(sumlog, hend, hin, nbD);
    scan_c<<<dim3(DI / 256, nb, NC), blk, 0, stream>>>(dt, u, sf.A_log, hin, Ct, z, y, nbD);

    // 5) out_proj -> out (f32)
    gemm_bt<2><<<dim3(DM / BN, Mrows / BM), blk, 0, stream>>>(
        y, wb.Wo, Mrows, DM, DI, nullptr, nullptr, nullptr, nullptr, nullptr, out);
}

extern "C" void kernel_launch(void* const* d_in, const int* in_sizes, int n_in,
                              void* d_out, int out_size, void* d_ws, size_t ws_size,
                              hipStream_t stream)
{
    const float* x     = (const float*)d_in[0];
    const float* Wi    = (const float*)d_in[1];
    const float* Wconv = (const float*)d_in[2];
    const float* bconv = (const float*)d_in[3];
    const float* Wdt   = (const float*)d_in[4];
    const float* bdt   = (const float*)d_in[5];
    const float* WB    = (const float*)d_in[6];
    const float* WC    = (const float*)d_in[7];
    const float* Wo    = (const float*)d_in[8];
    const float* A_log = (const float*)d_in[9];

    const size_t nWi = (size_t)2 * DI * DM;   // 4.19M
    const size_t nWp = (size_t)DI * DI;       // 4.19M
    const size_t nWo = (size_t)DM * DI;       // 2.10M

    // weight casts live at the END of ws (shared by all paths)
    const size_t wbytes = (nWi + 3 * nWp + nWo) * 2;
    char* q = (char*)d_ws + ws_size - wbytes;
    u16* Wi_b   = (u16*)q; q += nWi * 2;
    u16* Wcat_b = (u16*)q; q += 3 * nWp * 2;   // [Wdt; WB; WC]
    u16* Wo_b   = (u16*)q; q += nWo * 2;

    dim3 blk(256);
    cast_f2b<<<dim3((unsigned)(nWi / 1024)), blk, 0, stream>>>(Wi,  Wi_b, (long)nWi);
    cast_f2b<<<dim3((unsigned)(nWp / 1024)), blk, 0, stream>>>(Wdt, Wcat_b,            (long)nWp);
    cast_f2b<<<dim3((unsigned)(nWp / 1024)), blk, 0, stream>>>(WB,  Wcat_b + nWp,      (long)nWp);
    cast_f2b<<<dim3((unsigned)(nWp / 1024)), blk, 0, stream>>>(WC,  Wcat_b + 2 * nWp,  (long)nWp);
    cast_f2b<<<dim3((unsigned)(nWo / 1024)), blk, 0, stream>>>(Wo,  Wo_b, (long)nWo);

    WeightsB wb{Wi_b, Wcat_b, Wo_b};
    SmallF   sf{Wconv, bconv, bdt, A_log};

    // big-buffer need for nb batches (xb aliased into xc):
    auto need = [&](int nb) -> size_t {
        size_t nE = (size_t)nb * LSEQ * DI;
        return 5 * nE * 2 + 3 * (size_t)nb * DI * NC * 4;
    };

    if (ws_size >= need(4) + wbytes) {
        run_pipeline(4, x, (float*)d_out, (char*)d_ws, wb, sf, stream);
    } else if (ws_size >= need(2) + wbytes) {
        for (int b = 0; b < 4; b += 2)
            run_pipeline(2, x + (size_t)b * LSEQ * DM,
                         (float*)d_out + (size_t)b * LSEQ * DM,
                         (char*)d_ws, wb, sf, stream);
    } else {
        for (int b = 0; b < 4; ++b)
            run_pipeline(1, x + (size_t)b * LSEQ * DM,
                         (float*)d_out + (size_t)b * LSEQ * DM,
                         (char*)d_ws, wb, sf, stream);
    }
}